// Round 3
// baseline (674.233 us; speedup 1.0000x reference)
//
#include <hip/hip_runtime.h>
#include <math.h>

#define BB 192
#define DD 2048
#define HH 128

// D * log(2*pi) in f64, rounds to the same f32 the reference produces
#define D_LOG2PI 3763.9722320063395f

typedef float f32x4 __attribute__((ext_vector_type(4)));

// ---------------------------------------------------------------------------
// Kernel 1: fused 3-layer MLP head. One block = (2 rows, 1 head), 512 threads.
// All weight loads are lane-consecutive (coalesced); each weight fetch is
// shared by 2 rows, halving L2 traffic vs round 1.
//   head 0 = mu, head 1 = logvar. Writes mu, scale, inv_var, logdet to ws.
// ---------------------------------------------------------------------------
__global__ __launch_bounds__(512) void head_kernel(
    const float* __restrict__ q,
    const float* __restrict__ mw1, const float* __restrict__ mb1,
    const float* __restrict__ mw2, const float* __restrict__ mb2,
    const float* __restrict__ mw3, const float* __restrict__ mb3,
    const float* __restrict__ lw1, const float* __restrict__ lb1,
    const float* __restrict__ lw2, const float* __restrict__ lb2,
    const float* __restrict__ lw3, const float* __restrict__ lb3,
    float* __restrict__ mu_out, float* __restrict__ scale_out,
    float* __restrict__ invvar_out, float* __restrict__ logdet_out)
{
    const int row0 = blockIdx.x * 2;          // 96 blocks.x -> rows {2b, 2b+1}
    const int head = blockIdx.y;              // 0 = mu, 1 = logvar
    const float* W1 = head ? lw1 : mw1;
    const float* B1 = head ? lb1 : mb1;
    const float* W2 = head ? lw2 : mw2;
    const float* B2 = head ? lb2 : mb2;
    const float* W3 = head ? lw3 : mw3;
    const float* B3 = head ? lb3 : mb3;

    __shared__ float qrow[2 * DD];            // 16 KB
    __shared__ float h1[2][HH];
    __shared__ float h2[2][HH];
    __shared__ float red[8][2];

    const int t    = threadIdx.x;
    const int wave = t >> 6;
    const int lane = t & 63;
    const int half = lane >> 5;               // half-wave id
    const int kl   = lane & 31;               // lane within half-wave

    // stage 2 q rows (contiguous 16 KB, coalesced)
    {
        const f32x4* src = (const f32x4*)(q + (size_t)row0 * DD);
        f32x4* dst = (f32x4*)qrow;
        #pragma unroll
        for (int it = 0; it < (2 * DD / 4) / 512; ++it)
            dst[it * 512 + t] = src[it * 512 + t];
    }
    __syncthreads();

    // ---- layer 1: D -> H. Wave w owns outputs [16w, 16w+16); 64 lanes split K
    //      contiguously -> every weight load is a coalesced 1 KB wave-load. ----
    {
        const f32x4* q0 = (const f32x4*)qrow;
        const f32x4* q1 = (const f32x4*)(qrow + DD);
        for (int oi = 0; oi < 16; ++oi) {
            const int o = wave * 16 + oi;
            const f32x4* w4 = (const f32x4*)(W1 + (size_t)o * DD);
            float a0 = 0.f, a1 = 0.f;
            #pragma unroll
            for (int k = 0; k < DD / 4 / 64; ++k) {        // 8 iters
                f32x4 w  = w4[k * 64 + lane];
                f32x4 x0 = q0[k * 64 + lane];
                f32x4 x1 = q1[k * 64 + lane];
                a0 += w.x * x0.x + w.y * x0.y + w.z * x0.z + w.w * x0.w;
                a1 += w.x * x1.x + w.y * x1.y + w.z * x1.z + w.w * x1.w;
            }
            #pragma unroll
            for (int off = 32; off; off >>= 1) {
                a0 += __shfl_xor(a0, off);
                a1 += __shfl_xor(a1, off);
            }
            if (lane == 0) {
                const float b = B1[o];
                h1[0][o] = fmaxf(a0 + b, 0.f);
                h1[1][o] = fmaxf(a1 + b, 0.f);
            }
        }
    }
    __syncthreads();

    // ---- layer 2: H -> H. Half-wave (32 lanes x f32x4 = K=128) per output. ----
    {
        const f32x4* x0 = (const f32x4*)h1[0];
        const f32x4* x1 = (const f32x4*)h1[1];
        #pragma unroll
        for (int pi = 0; pi < 8; ++pi) {
            const int o = wave * 16 + pi * 2 + half;
            const f32x4* w4 = (const f32x4*)(W2 + (size_t)o * HH);
            f32x4 w  = w4[kl];
            f32x4 v0 = x0[kl];
            f32x4 v1 = x1[kl];
            float a0 = w.x * v0.x + w.y * v0.y + w.z * v0.z + w.w * v0.w;
            float a1 = w.x * v1.x + w.y * v1.y + w.z * v1.z + w.w * v1.w;
            #pragma unroll
            for (int off = 16; off; off >>= 1) {
                a0 += __shfl_xor(a0, off);
                a1 += __shfl_xor(a1, off);
            }
            if (kl == 0) {
                const float b = B2[o];
                h2[0][o] = fmaxf(a0 + b, 0.f);
                h2[1][o] = fmaxf(a1 + b, 0.f);
            }
        }
    }
    __syncthreads();

    // ---- layer 3: H -> D. Half-wave per output; wave w owns [256w, 256w+256).
    //      Adjacent half-waves read adjacent W3 rows -> coalesced 1 KB/wave. ----
    float slv0 = 0.f, slv1 = 0.f;
    {
        const f32x4* x0 = (const f32x4*)h2[0];
        const f32x4* x1 = (const f32x4*)h2[1];
        for (int pi = 0; pi < 128; ++pi) {
            const int o = wave * 256 + pi * 2 + half;
            const f32x4* w4 = (const f32x4*)(W3 + (size_t)o * HH);
            f32x4 w  = w4[kl];
            f32x4 v0 = x0[kl];
            f32x4 v1 = x1[kl];
            float a0 = w.x * v0.x + w.y * v0.y + w.z * v0.z + w.w * v0.w;
            float a1 = w.x * v1.x + w.y * v1.y + w.z * v1.z + w.w * v1.w;
            #pragma unroll
            for (int off = 16; off; off >>= 1) {
                a0 += __shfl_xor(a0, off);
                a1 += __shfl_xor(a1, off);
            }
            if (kl == 0) {
                const float b = B3[o];
                const float r0 = fmaxf(a0 + b, 0.f);
                const float r1 = fmaxf(a1 + b, 0.f);
                if (head == 0) {
                    mu_out[(size_t)row0 * DD + o]       = r0;
                    mu_out[(size_t)(row0 + 1) * DD + o] = r1;
                } else {
                    const float var0 = expf(0.5f * r0);   // covariance diagonal
                    const float var1 = expf(0.5f * r1);
                    scale_out [(size_t)row0 * DD + o]       = sqrtf(var0);
                    scale_out [(size_t)(row0 + 1) * DD + o] = sqrtf(var1);
                    invvar_out[(size_t)row0 * DD + o]       = 1.0f / var0;
                    invvar_out[(size_t)(row0 + 1) * DD + o] = 1.0f / var1;
                    slv0 += r0;
                    slv1 += r1;
                }
            }
        }
    }

    if (head == 1) {
        #pragma unroll
        for (int off = 32; off; off >>= 1) {
            slv0 += __shfl_down(slv0, off);
            slv1 += __shfl_down(slv1, off);
        }
        if (lane == 0) { red[wave][0] = slv0; red[wave][1] = slv1; }
        __syncthreads();
        if (t == 0) {
            float s0 = 0.f, s1 = 0.f;
            #pragma unroll
            for (int w = 0; w < 8; ++w) { s0 += red[w][0]; s1 += red[w][1]; }
            logdet_out[row0]     = 0.5f * s0;
            logdet_out[row0 + 1] = 0.5f * s1;
        }
    }
}

// ---------------------------------------------------------------------------
// Kernel 2: streaming p = mu + eps*scale, maha reduce, log_prob.
// One WAVE per (i,j): 8 unrolled f32x4 iterations keep >=4 eps loads in
// flight per wave; shuffle-only reduce (no LDS, no barrier).
// ---------------------------------------------------------------------------
__global__ __launch_bounds__(64) void sample_logprob_kernel(
    const float* __restrict__ eps,
    const float* __restrict__ mu, const float* __restrict__ scale,
    const float* __restrict__ invvar, const float* __restrict__ logdet,
    float* __restrict__ p_out, float* __restrict__ lp_out)
{
    const int i = blockIdx.x;   // i fastest -> consecutive blocks share j-row in L2
    const int j = blockIdx.y;
    const int t = threadIdx.x;

    const size_t base = ((size_t)(i * BB + j)) * DD;
    const f32x4* e4  = (const f32x4*)(eps + base);
    const f32x4* m4  = (const f32x4*)(mu + (size_t)j * DD);
    const f32x4* s4  = (const f32x4*)(scale + (size_t)j * DD);
    const f32x4* iv4 = (const f32x4*)(invvar + (size_t)j * DD);
    f32x4* p4 = (f32x4*)(p_out + base);

    float acc = 0.f;
    #pragma unroll 4
    for (int it = 0; it < DD / 256; ++it) {               // 8 iters
        const int idx = it * 64 + t;
        f32x4 e  = __builtin_nontemporal_load(&e4[idx]);  // streamed, no reuse
        f32x4 m  = m4[idx];                               // L2-hot per-j rows
        f32x4 s  = s4[idx];
        f32x4 iv = iv4[idx];
        f32x4 pv;
        pv.x = m.x + e.x * s.x;
        pv.y = m.y + e.y * s.y;
        pv.z = m.z + e.z * s.z;
        pv.w = m.w + e.w * s.w;
        const float dx = pv.x - m.x, dy = pv.y - m.y, dz = pv.z - m.z, dw = pv.w - m.w;
        acc += dx * dx * iv.x;
        acc += dy * dy * iv.y;
        acc += dz * dz * iv.z;
        acc += dw * dw * iv.w;
        __builtin_nontemporal_store(pv, &p4[idx]);        // streamed, no reuse
    }

    #pragma unroll
    for (int off = 32; off; off >>= 1) acc += __shfl_down(acc, off);
    if (t == 0)
        lp_out[(size_t)i * BB + j] = -0.5f * (acc + D_LOG2PI) - 0.5f * logdet[j];
}

extern "C" void kernel_launch(void* const* d_in, const int* in_sizes, int n_in,
                              void* d_out, int out_size, void* d_ws, size_t ws_size,
                              hipStream_t stream) {
    (void)in_sizes; (void)n_in; (void)out_size; (void)ws_size;
    const float* q    = (const float*)d_in[0];
    const float* eps  = (const float*)d_in[1];
    const float* mw1  = (const float*)d_in[2];
    const float* mb1  = (const float*)d_in[3];
    const float* mw2  = (const float*)d_in[4];
    const float* mb2  = (const float*)d_in[5];
    const float* mw3  = (const float*)d_in[6];
    const float* mb3  = (const float*)d_in[7];
    const float* lw1  = (const float*)d_in[8];
    const float* lb1  = (const float*)d_in[9];
    const float* lw2  = (const float*)d_in[10];
    const float* lb2  = (const float*)d_in[11];
    const float* lw3  = (const float*)d_in[12];
    const float* lb3  = (const float*)d_in[13];

    float* ws     = (float*)d_ws;
    float* mu     = ws;                          // B*D
    float* scale  = ws + (size_t)BB * DD;        // B*D
    float* invvar = ws + 2 * (size_t)BB * DD;    // B*D
    float* logdet = ws + 3 * (size_t)BB * DD;    // B

    float* p  = (float*)d_out;                   // B*B*D
    float* lp = p + (size_t)BB * BB * DD;        // B*B

    head_kernel<<<dim3(BB / 2, 2), 512, 0, stream>>>(
        q, mw1, mb1, mw2, mb2, mw3, mb3, lw1, lb1, lw2, lb2, lw3, lb3,
        mu, scale, invvar, logdet);

    sample_logprob_kernel<<<dim3(BB, BB), 64, 0, stream>>>(
        eps, mu, scale, invvar, logdet, p, lp);
}